// Round 15
// baseline (67.740 us; speedup 1.0000x reference)
//
#include <hip/hip_runtime.h>
#include <stdint.h>

#define S 1024
#define B 32
#define D 1024
#define NCH 32           // s-chunks
#define CH (S / NCH)     // 32 rows per block
#define NPAIR (CH / 2)   // 16 pair-iterations
#define ECH 8            // e-chunks in kG
#define EC 128           // e per chunk

// ws layout (floats)
#define PG_OFF   0                          // pg: ECH*B*D (1 MB)
#define LOG_OFF  (PG_OFF + ECH * B * D)     // logits: B*S
#define MARR_OFF (LOG_OFF + B * S)          // NCH*B
#define LARR_OFF (MARR_OFF + NCH * B)       // NCH*B
#define PACC_OFF (LARR_OFF + NCH * B)       // NCH*B*D (4 MB)
#define DUP_OFF  (PACC_OFF + NCH * B * D)   // probe: duplicate kB outputs

typedef const __attribute__((address_space(1))) unsigned int* gas_t;
typedef __attribute__((address_space(3))) unsigned int* las_t;

// kG: pg[z][b][d] = sum_{e in chunk z} h[b,e] * W[e,d].
__global__ __launch_bounds__(256) void kG(const float* __restrict__ hid,
                                          const float* __restrict__ W,
                                          float* __restrict__ ws) {
    const int d  = blockIdx.x * 256 + threadIdx.x;
    const int b  = blockIdx.y;
    const int e0 = blockIdx.z * EC;
    const float* __restrict__ hrow = hid + b * D;
    float acc = 0.f;
    #pragma unroll 8
    for (int e = e0; e < e0 + EC; ++e)
        acc = fmaf(hrow[e], W[(size_t)e * D + d], acc);
    ws[PG_OFF + ((size_t)blockIdx.z * B + b) * D + d] = acc;
}

// kB: LDS-staged flash stream (identical to R14), outputs parameterized so
// the probe can run it twice into disjoint regions.
__global__ __launch_bounds__(256) void kB(const float* __restrict__ enc,
                                          const float* __restrict__ pg,
                                          float* __restrict__ logits,
                                          float* __restrict__ marr,
                                          float* __restrict__ larr,
                                          float* __restrict__ pacc) {
    const int tid  = threadIdx.x;
    const int lane = tid & 63;
    const int wid  = tid >> 6;
    const int c    = blockIdx.x;
    const int b    = blockIdx.y;

    __shared__ float tile[2][2 * D];        // 16 KB: dbuf x (2 rows x 1024)
    __shared__ float red[2][2][4];          // [iter&1][row][wave]

    const int row0 = c * CH;

    auto stage = [&](int buf, int p) {
        #pragma unroll
        for (int r = 0; r < 2; ++r) {
            const float* gp = enc + ((size_t)(row0 + 2 * p + r) * B + b) * D
                            + wid * 256 + lane * 4;
            float* lp = &tile[buf][r * D + wid * 256];
            __builtin_amdgcn_global_load_lds((gas_t)(uintptr_t)gp,
                                             (las_t)(uintptr_t)lp, 16, 0, 0);
        }
    };

    stage(0, 0);

    float4 gv = {0.f, 0.f, 0.f, 0.f};
    #pragma unroll
    for (int ec = 0; ec < ECH; ++ec) {
        float4 v = ((const float4*)(pg + (size_t)(ec * B + b) * D))[tid];
        gv.x += v.x; gv.y += v.y; gv.z += v.z; gv.w += v.w;
    }
    __syncthreads();

    float m = -3.0e38f, l = 0.f;
    float4 acc = {0.f, 0.f, 0.f, 0.f};

    for (int p = 0; p < NPAIR; ++p) {
        const int cur = p & 1;
        if (p + 1 < NPAIR) stage(cur ^ 1, p + 1);

        const float4* t4 = (const float4*)tile[cur];
        float4 e0 = t4[tid];
        float4 e1 = t4[256 + tid];
        float pd0 = e0.x * gv.x + e0.y * gv.y + e0.z * gv.z + e0.w * gv.w;
        float pd1 = e1.x * gv.x + e1.y * gv.y + e1.z * gv.z + e1.w * gv.w;
        #pragma unroll
        for (int off = 1; off < 64; off <<= 1) {
            pd0 += __shfl_xor(pd0, off, 64);
            pd1 += __shfl_xor(pd1, off, 64);
        }
        if (lane == 0) { red[p & 1][0][wid] = pd0; red[p & 1][1][wid] = pd1; }
        __syncthreads();

        float l0 = red[p & 1][0][0] + red[p & 1][0][1]
                 + red[p & 1][0][2] + red[p & 1][0][3];
        float l1 = red[p & 1][1][0] + red[p & 1][1][1]
                 + red[p & 1][1][2] + red[p & 1][1][3];
        if (tid == 0) {
            logits[b * S + row0 + 2 * p]     = l0;
            logits[b * S + row0 + 2 * p + 1] = l1;
        }
        float mn  = fmaxf(m, l0);
        float sc0 = __expf(m - mn);
        float pA  = __expf(l0 - mn);
        float mn2 = fmaxf(mn, l1);
        float sc1 = __expf(mn - mn2);
        float pB  = __expf(l1 - mn2);
        float s01 = sc0 * sc1;
        float a0  = pA * sc1;
        l = l * s01 + a0 + pB;
        acc.x = acc.x * s01 + a0 * e0.x + pB * e1.x;
        acc.y = acc.y * s01 + a0 * e0.y + pB * e1.y;
        acc.z = acc.z * s01 + a0 * e0.z + pB * e1.z;
        acc.w = acc.w * s01 + a0 * e0.w + pB * e1.w;
        m = mn2;
    }

    ((float4*)pacc)[(size_t)(c * B + b) * (D / 4) + tid] = acc;
    if (tid == 0) { marr[c * B + b] = m; larr[c * B + b] = l; }
}

// kC: combine NCH partials -> reps; normalize logits -> alpha. Grid (4, B).
__global__ __launch_bounds__(256) void kC(float* __restrict__ out,
                                          const float* __restrict__ ws) {
    const int tid = threadIdx.x;
    const int q   = blockIdx.x;
    const int b   = blockIdx.y;
    const float* logits = ws + LOG_OFF;
    const float* marr   = ws + MARR_OFF;
    const float* larr   = ws + LARR_OFF;
    const float* pacc   = ws + PACC_OFF;

    __shared__ float shm[NCH], shl[NCH], shf[NCH];
    if (tid < NCH) { shm[tid] = marr[tid * B + b]; shl[tid] = larr[tid * B + b]; }
    __syncthreads();
    float mg = -3.0e38f;
    #pragma unroll
    for (int cc = 0; cc < NCH; ++cc) mg = fmaxf(mg, shm[cc]);
    if (tid < NCH) shf[tid] = __expf(shm[tid] - mg);
    __syncthreads();
    float lg = 0.f;
    #pragma unroll
    for (int cc = 0; cc < NCH; ++cc) lg += shl[cc] * shf[cc];
    const float inv = 1.f / lg;

    if (tid < 64) {
        const int d4 = q * 64 + tid;
        float4 racc = {0.f, 0.f, 0.f, 0.f};
        #pragma unroll 4
        for (int cc = 0; cc < NCH; ++cc) {
            float  fc = shf[cc];
            float4 v  = ((const float4*)pacc)[(size_t)(cc * B + b) * (D / 4) + d4];
            racc.x += v.x * fc; racc.y += v.y * fc;
            racc.z += v.z * fc; racc.w += v.w * fc;
        }
        float4 rep = {racc.x * inv, racc.y * inv, racc.z * inv, racc.w * inv};
        ((float4*)out)[b * (D / 4) + d4] = rep;                    // reps [B,1,D]
    }
    const int s = q * 256 + tid;
    out[B * D + b * S + s] = __expf(logits[b * S + s] - mg) * inv; // alpha [B,1,S]
}

extern "C" void kernel_launch(void* const* d_in, const int* in_sizes, int n_in,
                              void* d_out, int out_size, void* d_ws, size_t ws_size,
                              hipStream_t stream) {
    const float* hid = (const float*)d_in[0];  // (2,B,H) flat == h[B, D]
    const float* enc = (const float*)d_in[1];  // (S,B,D)
    const float* W   = (const float*)d_in[2];  // (D,D)
    // d_in[3] = bias: per-b constant in logits -> cancels in softmax.

    float* out = (float*)d_out;
    float* ws  = (float*)d_ws;

    float* logits = ws + LOG_OFF;
    float* marr   = ws + MARR_OFF;
    float* larr   = ws + LARR_OFF;
    float* pacc   = ws + PACC_OFF;

    // dup region (probe): kB run twice; kC reads only the first set.
    float* dlog  = ws + DUP_OFF;
    float* dmarr = dlog + B * S;
    float* dlarr = dmarr + NCH * B;
    float* dpacc = dlarr + NCH * B;

    kG<<<dim3(D / 256, B, ECH), 256, 0, stream>>>(hid, W, ws);
    kB<<<dim3(NCH, B), 256, 0, stream>>>(enc, ws + PG_OFF, logits, marr, larr, pacc);
    kB<<<dim3(NCH, B), 256, 0, stream>>>(enc, ws + PG_OFF, dlog, dmarr, dlarr, dpacc);
    kC<<<dim3(4, B), 256, 0, stream>>>(out, ws);
}

// Round 16
// 42.122 us; speedup vs baseline: 1.6082x; 1.6082x over previous
//
#include <hip/hip_runtime.h>
#include <stdint.h>

#define S 1024
#define B 32
#define D 1024
#define NCH 32           // s-chunks in kB
#define CH (S / NCH)     // 32 rows per block
#define NPAIR (CH / 2)   // 16 pair-iterations
#define GECH 32          // e-chunks in kG3
#define GEC 32           // e per chunk

// ws layout (floats)
#define PG_OFF   0                          // pg32: GECH*B*D (4 MB)
#define G_OFF    (PG_OFF + GECH * B * D)    // g: B*D (128 KB)
#define LOG_OFF  (G_OFF + B * D)            // logits: B*S
#define MARR_OFF (LOG_OFF + B * S)          // NCH*B
#define LARR_OFF (MARR_OFF + NCH * B)       // NCH*B
#define PACC_OFF (LARR_OFF + NCH * B)       // NCH*B*D (4 MB)

typedef const __attribute__((address_space(1))) unsigned int* gas_t;
typedef __attribute__((address_space(3))) unsigned int* las_t;

// kG3: pg32[ec][b][d-slice] = sum_{e in 32-chunk} h[b,e] * W[e,d].
// Grid (32 dc, 32 ec) = 1024 blocks (4/CU): W read EXACTLY ONCE (32x32
// tile/block) AND full TLP. 256 thr = 32 b x 8 dq. No atomics.
__global__ __launch_bounds__(256) void kG3(const float* __restrict__ hid,
                                           const float* __restrict__ W,
                                           float* __restrict__ ws) {
    const int tid = threadIdx.x;
    const int dc  = blockIdx.x;              // 32-d slice
    const int ec  = blockIdx.y;              // 32-e chunk
    __shared__ float h_sh[GEC * 33];         // [e][b], padded
    #pragma unroll
    for (int k = 0; k < (GEC * B) / 256; ++k) {
        int lin = tid + k * 256;
        int e = lin & (GEC - 1);             // e fastest: coalesced 128B runs
        int b = lin >> 5;
        h_sh[e * 33 + b] = hid[b * D + ec * GEC + e];
    }
    __syncthreads();

    const int b  = tid >> 3;                 // 0..31
    const int dq = tid & 7;                  // float4 within 32-d slice
    const float4* W4 = (const float4*)W;
    float4 a4 = {0.f, 0.f, 0.f, 0.f};
    #pragma unroll 8
    for (int e = 0; e < GEC; ++e) {
        float  h = h_sh[e * 33 + b];
        float4 w = W4[(size_t)(ec * GEC + e) * (D / 4) + dc * 8 + dq];
        a4.x = fmaf(h, w.x, a4.x);
        a4.y = fmaf(h, w.y, a4.y);
        a4.z = fmaf(h, w.z, a4.z);
        a4.w = fmaf(h, w.w, a4.w);
    }
    ((float4*)(ws + PG_OFF + ((size_t)ec * B + b) * D + dc * 32))[dq] = a4;
}

// kR: g = sum over 32 pg32 slices. 32 blocks; 32 independent loads/thread.
__global__ __launch_bounds__(256) void kR(float* __restrict__ ws) {
    const int idx = blockIdx.x * 256 + threadIdx.x;   // 0..8191 float4 of g
    const float4* pg4 = (const float4*)(ws + PG_OFF);
    float4 s4 = {0.f, 0.f, 0.f, 0.f};
    #pragma unroll
    for (int ec = 0; ec < GECH; ++ec) {
        float4 v = pg4[(size_t)ec * (B * D / 4) + idx];
        s4.x += v.x; s4.y += v.y; s4.z += v.z; s4.w += v.w;
    }
    ((float4*)(ws + G_OFF))[idx] = s4;
}

// kB: LDS-staged flash stream (R14/R15 structure); gv = 4 direct loads from
// g (L2-hot). One barrier per pair-iteration; no merge epilogue.
__global__ __launch_bounds__(256) void kB(const float* __restrict__ enc,
                                          float* __restrict__ ws) {
    const int tid  = threadIdx.x;
    const int lane = tid & 63;
    const int wid  = tid >> 6;
    const int c    = blockIdx.x;
    const int b    = blockIdx.y;

    const float* g = ws + G_OFF;
    float* logits = ws + LOG_OFF;
    float* marr   = ws + MARR_OFF;
    float* larr   = ws + LARR_OFF;
    float* pacc   = ws + PACC_OFF;

    __shared__ float tile[2][2 * D];        // 16 KB: dbuf x (2 rows x 1024)
    __shared__ float red[2][2][4];          // [iter&1][row][wave]

    const int row0 = c * CH;

    auto stage = [&](int buf, int p) {
        #pragma unroll
        for (int r = 0; r < 2; ++r) {
            const float* gp = enc + ((size_t)(row0 + 2 * p + r) * B + b) * D
                            + wid * 256 + lane * 4;
            float* lp = &tile[buf][r * D + wid * 256];
            __builtin_amdgcn_global_load_lds((gas_t)(uintptr_t)gp,
                                             (las_t)(uintptr_t)lp, 16, 0, 0);
        }
    };

    stage(0, 0);                             // async: tile[0] <- pair 0

    float4 gv = ((const float4*)(g + b * D))[tid];   // thread's d-slice of g
    __syncthreads();                         // tile[0] ready

    float m = -3.0e38f, l = 0.f;
    float4 acc = {0.f, 0.f, 0.f, 0.f};

    for (int p = 0; p < NPAIR; ++p) {
        const int cur = p & 1;
        if (p + 1 < NPAIR) stage(cur ^ 1, p + 1);

        const float4* t4 = (const float4*)tile[cur];
        float4 e0 = t4[tid];
        float4 e1 = t4[256 + tid];
        float pd0 = e0.x * gv.x + e0.y * gv.y + e0.z * gv.z + e0.w * gv.w;
        float pd1 = e1.x * gv.x + e1.y * gv.y + e1.z * gv.z + e1.w * gv.w;
        #pragma unroll
        for (int off = 1; off < 64; off <<= 1) {
            pd0 += __shfl_xor(pd0, off, 64);
            pd1 += __shfl_xor(pd1, off, 64);
        }
        if (lane == 0) { red[p & 1][0][wid] = pd0; red[p & 1][1][wid] = pd1; }
        __syncthreads();

        float l0 = red[p & 1][0][0] + red[p & 1][0][1]
                 + red[p & 1][0][2] + red[p & 1][0][3];
        float l1 = red[p & 1][1][0] + red[p & 1][1][1]
                 + red[p & 1][1][2] + red[p & 1][1][3];
        if (tid == 0) {
            logits[b * S + row0 + 2 * p]     = l0;
            logits[b * S + row0 + 2 * p + 1] = l1;
        }
        float mn  = fmaxf(m, l0);
        float sc0 = __expf(m - mn);
        float pA  = __expf(l0 - mn);
        float mn2 = fmaxf(mn, l1);
        float sc1 = __expf(mn - mn2);
        float pB  = __expf(l1 - mn2);
        float s01 = sc0 * sc1;
        float a0  = pA * sc1;
        l = l * s01 + a0 + pB;
        acc.x = acc.x * s01 + a0 * e0.x + pB * e1.x;
        acc.y = acc.y * s01 + a0 * e0.y + pB * e1.y;
        acc.z = acc.z * s01 + a0 * e0.z + pB * e1.z;
        acc.w = acc.w * s01 + a0 * e0.w + pB * e1.w;
        m = mn2;
    }

    ((float4*)pacc)[(size_t)(c * B + b) * (D / 4) + tid] = acc;
    if (tid == 0) { marr[c * B + b] = m; larr[c * B + b] = l; }
}

// kC: combine NCH partials -> reps; normalize logits -> alpha. Grid (4, B).
__global__ __launch_bounds__(256) void kC(float* __restrict__ out,
                                          const float* __restrict__ ws) {
    const int tid = threadIdx.x;
    const int q   = blockIdx.x;
    const int b   = blockIdx.y;
    const float* logits = ws + LOG_OFF;
    const float* marr   = ws + MARR_OFF;
    const float* larr   = ws + LARR_OFF;
    const float* pacc   = ws + PACC_OFF;

    __shared__ float shm[NCH], shl[NCH], shf[NCH];
    if (tid < NCH) { shm[tid] = marr[tid * B + b]; shl[tid] = larr[tid * B + b]; }
    __syncthreads();
    float mg = -3.0e38f;
    #pragma unroll
    for (int cc = 0; cc < NCH; ++cc) mg = fmaxf(mg, shm[cc]);
    if (tid < NCH) shf[tid] = __expf(shm[tid] - mg);
    __syncthreads();
    float lg = 0.f;
    #pragma unroll
    for (int cc = 0; cc < NCH; ++cc) lg += shl[cc] * shf[cc];
    const float inv = 1.f / lg;

    if (tid < 64) {
        const int d4 = q * 64 + tid;
        float4 racc = {0.f, 0.f, 0.f, 0.f};
        #pragma unroll 4
        for (int cc = 0; cc < NCH; ++cc) {
            float  fc = shf[cc];
            float4 v  = ((const float4*)pacc)[(size_t)(cc * B + b) * (D / 4) + d4];
            racc.x += v.x * fc; racc.y += v.y * fc;
            racc.z += v.z * fc; racc.w += v.w * fc;
        }
        float4 rep = {racc.x * inv, racc.y * inv, racc.z * inv, racc.w * inv};
        ((float4*)out)[b * (D / 4) + d4] = rep;                    // reps [B,1,D]
    }
    const int s = q * 256 + tid;
    out[B * D + b * S + s] = __expf(logits[b * S + s] - mg) * inv; // alpha [B,1,S]
}

extern "C" void kernel_launch(void* const* d_in, const int* in_sizes, int n_in,
                              void* d_out, int out_size, void* d_ws, size_t ws_size,
                              hipStream_t stream) {
    const float* hid = (const float*)d_in[0];  // (2,B,H) flat == h[B, D]
    const float* enc = (const float*)d_in[1];  // (S,B,D)
    const float* W   = (const float*)d_in[2];  // (D,D)
    // d_in[3] = bias: per-b constant in logits -> cancels in softmax.

    float* out = (float*)d_out;
    float* ws  = (float*)d_ws;

    kG3<<<dim3(32, GECH), 256, 0, stream>>>(hid, W, ws);
    kR<<<dim3(32), 256, 0, stream>>>(ws);
    kB<<<dim3(NCH, B), 256, 0, stream>>>(enc, ws);
    kC<<<dim3(4, B), 256, 0, stream>>>(out, ws);
}